// Round 2
// baseline (127.744 us; speedup 1.0000x reference)
//
#include <hip/hip_runtime.h>
#include <stdint.h>

#define NROWS 8192
#define DIM 128

typedef __bf16 bf16x8 __attribute__((ext_vector_type(8)));
typedef float floatx4 __attribute__((ext_vector_type(4)));

// ---------- helpers ----------
static __device__ __forceinline__ unsigned short f2bf(float f) {
    unsigned int u = __float_as_uint(f);
    unsigned int r = (u + 0x7FFFu + ((u >> 16) & 1u)) >> 16;   // RNE
    return (unsigned short)r;
}

// XOR swizzle on linear uint4 index g (per 512-uint4 chunk = 32 cols x 16 uint4):
// slot = (g&15) ^ (col&7). Bank group = 4*slot mod 32 -> 2-way only (free).
static __device__ __forceinline__ int swz(int g) {
    return (g & ~15) | ((g & 15) ^ ((g >> 4) & 7));
}

// ---------- kernel 1: normalize rows, emit bf16 a_hat + pos_dist ----------
__global__ __launch_bounds__(256) void normalize_kernel(
    const float* __restrict__ anchor, const float* __restrict__ positive,
    unsigned short* __restrict__ a_hat, float* __restrict__ pos_ws,
    float* __restrict__ out)
{
    if (blockIdx.x == 0 && threadIdx.x == 0) *out = 0.0f;   // replaces memset dispatch

    const int wave = threadIdx.x >> 6;
    const int lane = threadIdx.x & 63;
    const int row  = blockIdx.x * 4 + wave;

    const float2* arow = (const float2*)(anchor   + row * DIM);
    const float2* prow = (const float2*)(positive + row * DIM);
    float2 a = arow[lane];
    float2 p = prow[lane];

    float sa  = a.x * a.x + a.y * a.y;
    float sp  = p.x * p.x + p.y * p.y;
    float sap = a.x * p.x + a.y * p.y;
    #pragma unroll
    for (int off = 32; off; off >>= 1) {
        sa  += __shfl_xor(sa,  off);
        sp  += __shfl_xor(sp,  off);
        sap += __shfl_xor(sap, off);
    }
    float na  = fmaxf(sqrtf(sa), 1e-12f);
    float npn = fmaxf(sqrtf(sp), 1e-12f);
    float inv = 1.0f / na;

    ushort2 pack;
    pack.x = f2bf(a.x * inv);
    pack.y = f2bf(a.y * inv);
    ((ushort2*)a_hat)[row * 64 + lane] = pack;

    if (lane == 0)
        pos_ws[row] = 2.0f - 2.0f * sap / (na * npn);
}

// ---------- kernel 2: symmetric fused gram row-max, ZERO global atomics ----------
// Upper-triangle tiling: 256-row x 128-col tiles, rb in [0,32), cc in [2rb,64)
// -> 1056 tiles. Each tile (rb,cc) is the UNIQUE writer of:
//   P[cc][row]  row-max over its 128 cols, for its 256 rows   (plain stores)
//   Q[rb][col]  col-max over its 256 rows, for its 128 cols   (plain stores)
// (gram[i][j] == gram[j][i] bit-exactly: same k-order MFMA accumulation.)
// loss_kernel gathers the defined (rb,cc) partials per row. No atomicMax at
// all -> removes the 405K device-atomic storm (42 MB fetch / 73 MB write,
// ~90% stall) that dominated the previous version.
__global__ __launch_bounds__(256, 3) void gram_kernel(
    const unsigned short* __restrict__ a_hat, const int* __restrict__ labels,
    float* __restrict__ P, float* __restrict__ Q)
{
    const int tid  = threadIdx.x;
    const int lane = tid & 63;
    const int wave = tid >> 6;
    const int quad = lane >> 4;
    const int l15  = lane & 15;

    // triangle map: cum(rb) = rb*(65-rb); solve + fixup
    const int bid = blockIdx.x;
    int rb = (int)((65.0f - sqrtf(4225.0f - 4.0f * (float)bid)) * 0.5f);
    while (rb * (65 - rb) > bid) --rb;
    while ((rb + 1) * (64 - rb) <= bid) ++rb;
    const int cc = bid - rb * (65 - rb) + 2 * rb;

    const int rowBase = rb * 256 + wave * 64;   // this wave's 64 rows
    const int colBase = cc * 128;

    const uint4* A = (const uint4*)a_hat;       // row stride = 16 uint4 (256 B)

    __shared__ uint4  smem[2048];               // 32 KB: 128 cols x 16 uint4, swizzled
    __shared__ float  wcol[4][128];             // per-wave col maxes (plain stores)

    // issue B-tile stage loads first
    uint4 st[8];
    #pragma unroll
    for (int i = 0; i < 8; ++i)
        st[i] = A[colBase * 16 + i * 256 + tid];

    // A fragments: 64 rows = 4 slices of 16; lane holds A[l15][quad*8 k-chunk]
    bf16x8 afrag[4][4];
    #pragma unroll
    for (int ms = 0; ms < 4; ++ms) {
        const int r = rowBase + ms * 16 + l15;
        #pragma unroll
        for (int k = 0; k < 4; ++k)
            afrag[ms][k] = __builtin_bit_cast(bf16x8, A[r * 16 + k * 4 + quad]);
    }

    // output-row labels: row = rowBase + ms*16 + quad*4 + e  (int4-aligned)
    int4 rlab[4];
    #pragma unroll
    for (int ms = 0; ms < 4; ++ms)
        rlab[ms] = *(const int4*)(labels + rowBase + ms * 16 + quad * 4);

    #pragma unroll
    for (int i = 0; i < 8; ++i)
        smem[swz(i * 256 + tid)] = st[i];
    __syncthreads();

    float gmax[4][4];
    #pragma unroll
    for (int ms = 0; ms < 4; ++ms)
        #pragma unroll
        for (int e = 0; e < 4; ++e)
            gmax[ms][e] = -4.0f;

    #pragma unroll
    for (int cb = 0; cb < 4; ++cb) {
        const int C = colBase + cb * 32;
        const int clab0 = labels[C + l15];
        const int clab1 = labels[C + 16 + l15];

        bf16x8 bfrag[2][4];
        #pragma unroll
        for (int ns = 0; ns < 2; ++ns) {
            const int c = ns * 16 + l15;
            #pragma unroll
            for (int k = 0; k < 4; ++k) {
                const int g = cb * 512 + c * 16 + k * 4 + quad;
                bfrag[ns][k] = __builtin_bit_cast(bf16x8, smem[swz(g)]);
            }
        }

        #pragma unroll
        for (int ns = 0; ns < 2; ++ns) {
            const int cl = ns ? clab1 : clab0;
            float cmax = -4.0f;                    // col-max over this wave's 64 rows
            #pragma unroll
            for (int ms = 0; ms < 4; ++ms) {
                floatx4 acc = {0.f, 0.f, 0.f, 0.f};
                #pragma unroll
                for (int k = 0; k < 4; ++k)
                    acc = __builtin_amdgcn_mfma_f32_16x16x32_bf16(
                              afrag[ms][k], bfrag[ns][k], acc, 0, 0, 0);
                #pragma unroll
                for (int e = 0; e < 4; ++e) {
                    const int rle = (e == 0) ? rlab[ms].x : (e == 1) ? rlab[ms].y
                                  : (e == 2) ? rlab[ms].z : rlab[ms].w;
                    float v = (cl != rle) ? acc[e] : -4.0f;
                    gmax[ms][e] = fmaxf(gmax[ms][e], v);
                    cmax        = fmaxf(cmax, v);
                }
            }
            // combine the 4 quads (row groups) for col = C + ns*16 + l15
            cmax = fmaxf(cmax, __shfl_xor(cmax, 16));
            cmax = fmaxf(cmax, __shfl_xor(cmax, 32));
            if (quad == 0)
                wcol[wave][cb * 32 + ns * 16 + l15] = cmax;  // plain ds_write
        }
    }

    // row flush: reduce over the 16 cols (l15) per fragment row, plain store to P
    #pragma unroll
    for (int ms = 0; ms < 4; ++ms) {
        #pragma unroll
        for (int e = 0; e < 4; ++e) {
            float v = gmax[ms][e];
            #pragma unroll
            for (int off = 1; off < 16; off <<= 1)
                v = fmaxf(v, __shfl_xor(v, off));
            if (l15 == 0)
                P[cc * NROWS + rowBase + ms * 16 + quad * 4 + e] = v;
        }
    }

    // col flush: combine 4 waves' col maxes, plain store to Q
    __syncthreads();
    if (tid < 128) {
        float m = fmaxf(fmaxf(wcol[0][tid], wcol[1][tid]),
                        fmaxf(wcol[2][tid], wcol[3][tid]));
        Q[rb * NROWS + colBase + tid] = m;
    }
}

// ---------- kernel 3: gather partial maxes + final loss + mean ----------
__global__ __launch_bounds__(256) void loss_kernel(
    const float* __restrict__ pos_ws, const float* __restrict__ P,
    const float* __restrict__ Q, float* __restrict__ out)
{
    const int i  = blockIdx.x * 256 + threadIdx.x;
    const int rb = i >> 8;                       // uniform across the block

    float g = -4.0f;
    for (int cc = 2 * rb; cc < 64; ++cc)         // defined P partials for row i
        g = fmaxf(g, P[cc * NROWS + i]);
    for (int t = 0; t <= rb; ++t)                // defined Q partials for col i
        g = fmaxf(g, Q[t * NROWS + i]);

    float neg  = fmaxf(2.0f - 2.0f * g, 0.0f);
    float loss = fmaxf(pos_ws[i] - neg + 0.5f, 0.0f);

    #pragma unroll
    for (int off = 32; off; off >>= 1)
        loss += __shfl_xor(loss, off);

    __shared__ float ws[4];
    if ((threadIdx.x & 63) == 0) ws[threadIdx.x >> 6] = loss;
    __syncthreads();
    if (threadIdx.x == 0) {
        float s = ws[0] + ws[1] + ws[2] + ws[3];
        atomicAdd(out, s * (1.0f / 8192.0f));
    }
}

extern "C" void kernel_launch(void* const* d_in, const int* in_sizes, int n_in,
                              void* d_out, int out_size, void* d_ws, size_t ws_size,
                              hipStream_t stream) {
    const float* anchor   = (const float*)d_in[0];
    const float* positive = (const float*)d_in[1];
    const int*   labels   = (const int*)d_in[2];
    float* out = (float*)d_out;

    char* ws = (char*)d_ws;
    unsigned short* a_hat  = (unsigned short*)ws;                    // 2 MiB
    float*          pos_ws = (float*)(ws + 2 * 1024 * 1024);         // 32 KiB
    float*          P      = (float*)(ws + 4 * 1024 * 1024);         // 64*8192*4 = 2 MiB
    float*          Q      = (float*)(ws + 6 * 1024 * 1024);         // 32*8192*4 = 1 MiB

    normalize_kernel<<<NROWS / 4, 256, 0, stream>>>(anchor, positive, a_hat, pos_ws, out);
    gram_kernel<<<1056, 256, 0, stream>>>(a_hat, labels, P, Q);
    loss_kernel<<<NROWS / 256, 256, 0, stream>>>(pos_ws, P, Q, out);
}

// Round 3
// 106.080 us; speedup vs baseline: 1.2042x; 1.2042x over previous
//
#include <hip/hip_runtime.h>
#include <stdint.h>

#define NROWS 8192
#define DIM 128

typedef __bf16 bf16x8 __attribute__((ext_vector_type(8)));
typedef float floatx4 __attribute__((ext_vector_type(4)));

// ---------- helpers ----------
static __device__ __forceinline__ unsigned short f2bf(float f) {
    unsigned int u = __float_as_uint(f);
    unsigned int r = (u + 0x7FFFu + ((u >> 16) & 1u)) >> 16;   // RNE
    return (unsigned short)r;
}

// XOR swizzle on linear uint4 index g (per 512-uint4 chunk = 32 cols x 16 uint4):
// slot = (g&15) ^ (col&7). Bank group = 4*slot mod 32 -> 2-way only (free).
// Involution: swz(swz(g)) == g  (XOR term depends only on bits >=4, unchanged).
static __device__ __forceinline__ int swz(int g) {
    return (g & ~15) | ((g & 15) ^ ((g >> 4) & 7));
}

// async global->LDS, 16 B per lane: lane l lands at lptr + l*16 (linear).
static __device__ __forceinline__ void gload_lds16(const uint4* g, uint4* l) {
    __builtin_amdgcn_global_load_lds(
        (const __attribute__((address_space(1))) void*)g,
        (__attribute__((address_space(3))) void*)l, 16, 0, 0);
}

// ---------- kernel 1: normalize rows, emit bf16 a_hat + pos_dist ----------
__global__ __launch_bounds__(256) void normalize_kernel(
    const float* __restrict__ anchor, const float* __restrict__ positive,
    unsigned short* __restrict__ a_hat, float* __restrict__ pos_ws,
    float* __restrict__ out)
{
    if (blockIdx.x == 0 && threadIdx.x == 0) *out = 0.0f;   // replaces memset dispatch

    const int wave = threadIdx.x >> 6;
    const int lane = threadIdx.x & 63;
    const int row  = blockIdx.x * 4 + wave;

    const float2* arow = (const float2*)(anchor   + row * DIM);
    const float2* prow = (const float2*)(positive + row * DIM);
    float2 a = arow[lane];
    float2 p = prow[lane];

    float sa  = a.x * a.x + a.y * a.y;
    float sp  = p.x * p.x + p.y * p.y;
    float sap = a.x * p.x + a.y * p.y;
    #pragma unroll
    for (int off = 32; off; off >>= 1) {
        sa  += __shfl_xor(sa,  off);
        sp  += __shfl_xor(sp,  off);
        sap += __shfl_xor(sap, off);
    }
    float na  = fmaxf(sqrtf(sa), 1e-12f);
    float npn = fmaxf(sqrtf(sp), 1e-12f);
    float inv = 1.0f / na;

    ushort2 pack;
    pack.x = f2bf(a.x * inv);
    pack.y = f2bf(a.y * inv);
    ((ushort2*)a_hat)[row * 64 + lane] = pack;

    if (lane == 0)
        pos_ws[row] = 2.0f - 2.0f * sap / (na * npn);
}

// ---------- kernel 2: symmetric fused gram row-max ----------
// Upper-triangle tiling: 256-row x 128-col tiles, rb in [0,32), cc in [2rb,64)
// -> 1056 tiles. Tile (rb,cc) is the unique writer of P[cc][its 256 rows]
// (row-max over its 128 cols) and Q[rb][its 128 cols] (col-max over its 256
// rows; gram is bit-exactly symmetric). loss_kernel gathers.
//
// REGISTER BUDGET IS THE CONSTRAINT (learned rounds 1-2): live state must stay
// under the launch-bounds VGPR cap or the compiler spills afrag to scratch
// (was: VGPR_Count=84, 66 MB scratch writes, 55 us). Hence:
//  - __launch_bounds__(256, 2): cap 256 VGPRs (live ~150).
//  - B tile staged via global_load_lds (no st[] registers, no ds_write pass):
//    linear LDS dest + pre-swizzled GLOBAL source (swz is an involution).
__global__ __launch_bounds__(256, 2) void gram_kernel(
    const unsigned short* __restrict__ a_hat, const int* __restrict__ labels,
    float* __restrict__ P, float* __restrict__ Q)
{
    const int tid  = threadIdx.x;
    const int lane = tid & 63;
    const int wave = tid >> 6;
    const int quad = lane >> 4;
    const int l15  = lane & 15;

    // triangle map: cum(rb) = rb*(65-rb); solve + fixup
    const int bid = blockIdx.x;
    int rb = (int)((65.0f - sqrtf(4225.0f - 4.0f * (float)bid)) * 0.5f);
    while (rb * (65 - rb) > bid) --rb;
    while ((rb + 1) * (64 - rb) <= bid) ++rb;
    const int cc = bid - rb * (65 - rb) + 2 * rb;

    const int rowBase = rb * 256 + wave * 64;   // this wave's 64 rows
    const int colBase = cc * 128;

    const uint4* A = (const uint4*)a_hat;       // row stride = 16 uint4 (256 B)

    __shared__ uint4  smem[2048];               // 32 KB: 128 cols x 16 uint4, swizzled
    __shared__ float  wcol[4][128];             // per-wave col maxes

    // stage B tile: async global->LDS, linear dest slot s, source index swz(s)
    // so that smem[swz(g)] == A[colBase*16 + g] after the barrier.
    {
        const uint4* Gsrc = A + colBase * 16;
        #pragma unroll
        for (int i = 0; i < 8; ++i) {
            const int s = i * 256 + wave * 64 + lane;   // linear LDS slot
            gload_lds16(Gsrc + swz(s), &smem[i * 256 + wave * 64]);
        }
    }

    // A fragments: 64 rows = 4 slices of 16; lane holds A[l15][quad*8 k-chunk]
    bf16x8 afrag[4][4];
    #pragma unroll
    for (int ms = 0; ms < 4; ++ms) {
        const int r = rowBase + ms * 16 + l15;
        #pragma unroll
        for (int k = 0; k < 4; ++k)
            afrag[ms][k] = __builtin_bit_cast(bf16x8, A[r * 16 + k * 4 + quad]);
    }

    // output-row labels: row = rowBase + ms*16 + quad*4 + e  (int4-aligned)
    int4 rlab[4];
    #pragma unroll
    for (int ms = 0; ms < 4; ++ms)
        rlab[ms] = *(const int4*)(labels + rowBase + ms * 16 + quad * 4);

    float gmax[4][4];
    #pragma unroll
    for (int ms = 0; ms < 4; ++ms)
        #pragma unroll
        for (int e = 0; e < 4; ++e)
            gmax[ms][e] = -4.0f;

    __syncthreads();    // drains vmcnt (global_load_lds) before reads

    #pragma unroll
    for (int cb = 0; cb < 4; ++cb) {
        const int C = colBase + cb * 32;
        const int clab0 = labels[C + l15];
        const int clab1 = labels[C + 16 + l15];

        bf16x8 bfrag[2][4];
        #pragma unroll
        for (int ns = 0; ns < 2; ++ns) {
            const int c = ns * 16 + l15;
            #pragma unroll
            for (int k = 0; k < 4; ++k) {
                const int g = cb * 512 + c * 16 + k * 4 + quad;
                bfrag[ns][k] = __builtin_bit_cast(bf16x8, smem[swz(g)]);
            }
        }

        #pragma unroll
        for (int ns = 0; ns < 2; ++ns) {
            const int cl = ns ? clab1 : clab0;
            float cmax = -4.0f;                    // col-max over this wave's 64 rows
            #pragma unroll
            for (int ms = 0; ms < 4; ++ms) {
                floatx4 acc = {0.f, 0.f, 0.f, 0.f};
                #pragma unroll
                for (int k = 0; k < 4; ++k)
                    acc = __builtin_amdgcn_mfma_f32_16x16x32_bf16(
                              afrag[ms][k], bfrag[ns][k], acc, 0, 0, 0);
                #pragma unroll
                for (int e = 0; e < 4; ++e) {
                    const int rle = (e == 0) ? rlab[ms].x : (e == 1) ? rlab[ms].y
                                  : (e == 2) ? rlab[ms].z : rlab[ms].w;
                    float v = (cl != rle) ? acc[e] : -4.0f;
                    gmax[ms][e] = fmaxf(gmax[ms][e], v);
                    cmax        = fmaxf(cmax, v);
                }
            }
            // combine the 4 quads (row groups) for col = C + ns*16 + l15
            cmax = fmaxf(cmax, __shfl_xor(cmax, 16));
            cmax = fmaxf(cmax, __shfl_xor(cmax, 32));
            if (quad == 0)
                wcol[wave][cb * 32 + ns * 16 + l15] = cmax;  // plain ds_write
        }
    }

    // row flush: reduce over the 16 cols (l15) per fragment row, store to P
    #pragma unroll
    for (int ms = 0; ms < 4; ++ms) {
        #pragma unroll
        for (int e = 0; e < 4; ++e) {
            float v = gmax[ms][e];
            #pragma unroll
            for (int off = 1; off < 16; off <<= 1)
                v = fmaxf(v, __shfl_xor(v, off));
            if (l15 == 0)
                P[cc * NROWS + rowBase + ms * 16 + quad * 4 + e] = v;
        }
    }

    // col flush: combine 4 waves' col maxes, store to Q
    __syncthreads();
    if (tid < 128) {
        float m = fmaxf(fmaxf(wcol[0][tid], wcol[1][tid]),
                        fmaxf(wcol[2][tid], wcol[3][tid]));
        Q[rb * NROWS + colBase + tid] = m;
    }
}

// ---------- kernel 3: gather partial maxes + final loss + mean ----------
__global__ __launch_bounds__(256) void loss_kernel(
    const float* __restrict__ pos_ws, const float* __restrict__ P,
    const float* __restrict__ Q, float* __restrict__ out)
{
    const int i  = blockIdx.x * 256 + threadIdx.x;
    const int rb = i >> 8;                       // uniform across the block

    float g = -4.0f;
    for (int cc = 2 * rb; cc < 64; ++cc)         // defined P partials for row i
        g = fmaxf(g, P[cc * NROWS + i]);
    for (int t = 0; t <= rb; ++t)                // defined Q partials for col i
        g = fmaxf(g, Q[t * NROWS + i]);

    float neg  = fmaxf(2.0f - 2.0f * g, 0.0f);
    float loss = fmaxf(pos_ws[i] - neg + 0.5f, 0.0f);

    #pragma unroll
    for (int off = 32; off; off >>= 1)
        loss += __shfl_xor(loss, off);

    __shared__ float ws[4];
    if ((threadIdx.x & 63) == 0) ws[threadIdx.x >> 6] = loss;
    __syncthreads();
    if (threadIdx.x == 0) {
        float s = ws[0] + ws[1] + ws[2] + ws[3];
        atomicAdd(out, s * (1.0f / 8192.0f));
    }
}

extern "C" void kernel_launch(void* const* d_in, const int* in_sizes, int n_in,
                              void* d_out, int out_size, void* d_ws, size_t ws_size,
                              hipStream_t stream) {
    const float* anchor   = (const float*)d_in[0];
    const float* positive = (const float*)d_in[1];
    const int*   labels   = (const int*)d_in[2];
    float* out = (float*)d_out;

    char* ws = (char*)d_ws;
    unsigned short* a_hat  = (unsigned short*)ws;                    // 2 MiB
    float*          pos_ws = (float*)(ws + 2 * 1024 * 1024);         // 32 KiB
    float*          P      = (float*)(ws + 4 * 1024 * 1024);         // 64*8192*4 = 2 MiB
    float*          Q      = (float*)(ws + 6 * 1024 * 1024);         // 32*8192*4 = 1 MiB

    normalize_kernel<<<NROWS / 4, 256, 0, stream>>>(anchor, positive, a_hat, pos_ws, out);
    gram_kernel<<<1056, 256, 0, stream>>>(a_hat, labels, P, Q);
    loss_kernel<<<NROWS / 256, 256, 0, stream>>>(pos_ws, P, Q, out);
}